// Round 2
// baseline (1682.076 us; speedup 1.0000x reference)
//
#include <hip/hip_runtime.h>
#include <stdint.h>

#define N_V   20000
#define M_KP  160000
#define E_N   320000
#define SD    300
#define T_IT  3

typedef unsigned short bf16_t;

__device__ __forceinline__ float bf2f(bf16_t u) {
    return __uint_as_float(((unsigned)u) << 16);
}
__device__ __forceinline__ bf16_t f2bf(float f) {
    unsigned u = __float_as_uint(f);
    unsigned r = (u + 0x7FFFu + ((u >> 16) & 1u)) >> 16;
    return (bf16_t)r;
}

template<bool F32>
__device__ __forceinline__ float LD(const void* p, size_t i) {
    if (F32) return ((const float*)p)[i];
    return bf2f(((const bf16_t*)p)[i]);
}
template<bool F32>
__device__ __forceinline__ void ST(void* p, size_t i, float v) {
    if (F32) ((float*)p)[i] = v;
    else     ((bf16_t*)p)[i] = f2bf(v);
}

// ---------- dtype detect: flag=1 if float inputs are f32, 0 if bf16 ----------
__global__ void k_detect(const unsigned* __restrict__ w, int* __restrict__ flag) {
    __shared__ int cnt_s;
    if (threadIdx.x == 0) cnt_s = 0;
    __syncthreads();
    unsigned u = w[threadIdx.x];          // 128 dwords = 512B, safe for either dtype
    unsigned lo = u & 0xFFFFu;
    int e = (lo >> 7) & 0xFF;
    int plaus = (lo == 0u) || (e >= 96 && e <= 126);
    atomicAdd(&cnt_s, plaus);
    __syncthreads();
    if (threadIdx.x == 0) flag[0] = (cnt_s >= 64) ? 0 : 1;
}

// ---------- CSR build (dst-grouped edges) ----------
__global__ void k_zero(int* p, int n) {
    int i = blockIdx.x * blockDim.x + threadIdx.x;
    if (i < n) p[i] = 0;
}
__global__ void k_hist(const int* __restrict__ dst, int* __restrict__ cnt) {
    int e = blockIdx.x * blockDim.x + threadIdx.x;
    if (e < E_N) atomicAdd(&cnt[dst[e]], 1);
}
__global__ void k_scan(const int* __restrict__ cnt, int* __restrict__ offs,
                       int* __restrict__ cur) {
    __shared__ int buf[1024];
    __shared__ int carry_s;
    int tid = threadIdx.x;
    if (tid == 0) { carry_s = 0; offs[0] = 0; }
    __syncthreads();
    for (int base = 0; base < N_V; base += 1024) {
        int i = base + tid;
        int v = (i < N_V) ? cnt[i] : 0;
        buf[tid] = v;
        __syncthreads();
        for (int off = 1; off < 1024; off <<= 1) {
            int t = (tid >= off) ? buf[tid - off] : 0;
            __syncthreads();
            buf[tid] += t;
            __syncthreads();
        }
        int incl = buf[tid] + carry_s;
        if (i < N_V) { offs[i + 1] = incl; cur[i] = incl - v; }
        __syncthreads();
        if (tid == 1023) carry_s = incl;
        __syncthreads();
    }
}
__global__ void k_scatter(const int* __restrict__ src, const int* __restrict__ dst,
                          int* __restrict__ cur, int* __restrict__ esrc) {
    int e = blockIdx.x * blockDim.x + threadIdx.x;
    if (e < E_N) {
        int p = atomicAdd(&cur[dst[e]], 1);
        esrc[p] = src[e];
    }
}

// ---------- fused init MLP: kp(4)->64->128->300 + segmax8 -> kpmax [N,300] ----------
template<bool F32>
__global__ __launch_bounds__(256) void k_init_fused(
    const void* __restrict__ kp,
    const void* __restrict__ Wi0, const void* __restrict__ bi0,
    const void* __restrict__ Wi1, const void* __restrict__ bi1,
    const void* __restrict__ Wi2, const void* __restrict__ bi2,
    float* __restrict__ kpmax, const int* __restrict__ flag) {
    if ((flag[0] != 0) != F32) return;
    __shared__ float kps[256];        // 64 rows x 4
    __shared__ float h1s[64][64];     // 16 KB
    __shared__ float h2s[64 * 128];   // 32 KB
    int tid = threadIdx.x;
    int row0 = blockIdx.x * 64;       // 2500 blocks
    kps[tid] = LD<F32>(kp, (size_t)row0 * 4 + tid);
    __syncthreads();
    // layer0: h1[r][c] = relu(kp[r]@Wi0[:,c] + bi0[c])
    {
        int c = tid & 63;
        float w0 = LD<F32>(Wi0, c), w1 = LD<F32>(Wi0, 64 + c);
        float w2 = LD<F32>(Wi0, 128 + c), w3 = LD<F32>(Wi0, 192 + c);
        float b0 = LD<F32>(bi0, c);
        int rbase = (tid >> 6) * 16;
#pragma unroll
        for (int rr = 0; rr < 16; rr++) {
            int r = rbase + rr;
            float a = b0 + kps[r * 4] * w0 + kps[r * 4 + 1] * w1
                         + kps[r * 4 + 2] * w2 + kps[r * 4 + 3] * w3;
            h1s[r][c] = fmaxf(a, 0.f);
        }
    }
    __syncthreads();
    // layer1: h2[r][c] = relu(h1[r]@Wi1[:,c] + bi1[c])
    {
        int c = tid & 127;
        int rbase = (tid >> 7) * 32;
        float b1 = LD<F32>(bi1, c);
        float acc[32];
#pragma unroll
        for (int rr = 0; rr < 32; rr++) acc[rr] = b1;
        for (int k = 0; k < 64; k++) {
            float wv = LD<F32>(Wi1, (size_t)k * 128 + c);
#pragma unroll
            for (int rr = 0; rr < 32; rr++) acc[rr] += h1s[rbase + rr][k] * wv;
        }
#pragma unroll
        for (int rr = 0; rr < 32; rr++)
            h2s[(size_t)(rbase + rr) * 128 + c] = fmaxf(acc[rr], 0.f);
    }
    __syncthreads();
    // layer2 + segmax over 8 kp per vertex
    {
        int cx = tid & 63, rg = tid >> 6;
        float acc[16][5];
#pragma unroll
        for (int r = 0; r < 16; r++)
#pragma unroll
            for (int j = 0; j < 5; j++) acc[r][j] = 0.f;
        bool ok4 = (cx < SD - 256);
        for (int k = 0; k < 128; k++) {
            float w[5];
#pragma unroll
            for (int j = 0; j < 4; j++) w[j] = LD<F32>(Wi2, (size_t)k * SD + cx + 64 * j);
            w[4] = ok4 ? LD<F32>(Wi2, (size_t)k * SD + cx + 256) : 0.f;
#pragma unroll
            for (int r = 0; r < 16; r++) {
                float av = h2s[(rg * 16 + r) * 128 + k];
#pragma unroll
                for (int j = 0; j < 5; j++) acc[r][j] += av * w[j];
            }
        }
        int vbase = (row0 >> 3) + rg * 2;
#pragma unroll
        for (int half = 0; half < 2; half++) {
            int v = vbase + half;
#pragma unroll
            for (int j = 0; j < 5; j++) {
                int c = cx + 64 * j;
                if (c >= SD) continue;
                float m = acc[half * 8][j];
#pragma unroll
                for (int r = 1; r < 8; r++) m = fmaxf(m, acc[half * 8 + r][j]);
                kpmax[(size_t)v * SD + c] = fmaxf(m + LD<F32>(bi2, c), 0.f);
            }
        }
    }
}

// ---------- generic tiled f32 GEMM: C = [relu]( A[M,K]@W[K,N] + bias (+res) ) ----------
template<bool F32>
__global__ __launch_bounds__(256) void k_gemm(
    const float* __restrict__ A, const void* __restrict__ W,
    const void* __restrict__ bias, const float* res,
    float* C, int Mr, int K, int Nc, int do_relu, const int* __restrict__ flag) {
    if ((flag[0] != 0) != F32) return;
    __shared__ float As[16][65];
    __shared__ float Ws[16][64];
    int tid = threadIdx.x;
    int tx = tid & 15, ty = tid >> 4;
    int row0 = blockIdx.y * 64, col0 = blockIdx.x * 64;
    float acc[4][4] = {{0.f}};
    int lk = tid & 15, lr = tid >> 4;
    int ln = tid & 63, lk4 = tid >> 6;
    for (int k0 = 0; k0 < K; k0 += 16) {
#pragma unroll
        for (int i = 0; i < 4; i++) {
            int r = lr + i * 16;
            int gr = row0 + r, gk = k0 + lk;
            As[lk][r] = (gr < Mr && gk < K) ? A[(size_t)gr * K + gk] : 0.f;
        }
#pragma unroll
        for (int p = 0; p < 4; p++) {
            int kk = lk4 + p * 4;
            int gk = k0 + kk, gn = col0 + ln;
            Ws[kk][ln] = (gk < K && gn < Nc) ? LD<F32>(W, (size_t)gk * Nc + gn) : 0.f;
        }
        __syncthreads();
#pragma unroll
        for (int kk = 0; kk < 16; kk++) {
            float a[4], w[4];
#pragma unroll
            for (int i = 0; i < 4; i++) a[i] = As[kk][ty * 4 + i];
#pragma unroll
            for (int j = 0; j < 4; j++) w[j] = Ws[kk][tx * 4 + j];
#pragma unroll
            for (int i = 0; i < 4; i++)
#pragma unroll
                for (int j = 0; j < 4; j++) acc[i][j] += a[i] * w[j];
        }
        __syncthreads();
    }
#pragma unroll
    for (int i = 0; i < 4; i++) {
        int gr = row0 + ty * 4 + i;
        if (gr >= Mr) continue;
#pragma unroll
        for (int j = 0; j < 4; j++) {
            int gn = col0 + tx * 4 + j;
            if (gn >= Nc) continue;
            float c = acc[i][j] + LD<F32>(bias, gn);
            if (res) c += res[(size_t)gr * Nc + gn];
            if (do_relu) c = fmaxf(c, 0.f);
            C[(size_t)gr * Nc + gn] = c;
        }
    }
}

// ---------- dx = s @ Wh + bh  (one wave per vertex) ----------
template<bool F32>
__global__ void k_dx(const float* __restrict__ s, const void* __restrict__ Wh,
                     const void* __restrict__ bh, float* __restrict__ dx,
                     const int* __restrict__ flag) {
    if ((flag[0] != 0) != F32) return;
    int wv = threadIdx.x >> 6, lane = threadIdx.x & 63;
    int v = blockIdx.x * 4 + wv;
    if (v >= N_V) return;
    float p0 = 0.f, p1 = 0.f, p2 = 0.f;
    for (int d = lane; d < SD; d += 64) {
        float sv = s[(size_t)v * SD + d];
        p0 += sv * LD<F32>(Wh, d * 3 + 0);
        p1 += sv * LD<F32>(Wh, d * 3 + 1);
        p2 += sv * LD<F32>(Wh, d * 3 + 2);
    }
#pragma unroll
    for (int off = 32; off > 0; off >>= 1) {
        p0 += __shfl_down(p0, off);
        p1 += __shfl_down(p1, off);
        p2 += __shfl_down(p2, off);
    }
    if (lane == 0) {
        dx[v * 3 + 0] = p0 + LD<F32>(bh, 0);
        dx[v * 3 + 1] = p1 + LD<F32>(bh, 1);
        dx[v * 3 + 2] = p2 + LD<F32>(bh, 2);
    }
}

// ---------- a(=ua) += pos@Wf3 ; b(=bbag) = dx@Wf3 - pos@Wf3 ----------
template<bool F32>
__global__ void k_ab(const float* __restrict__ dx, const void* __restrict__ pos,
                     const void* __restrict__ Wf3, float* __restrict__ ua,
                     float* __restrict__ bbag, const int* __restrict__ flag) {
    if ((flag[0] != 0) != F32) return;
    int idx = blockIdx.x * blockDim.x + threadIdx.x;
    if (idx >= N_V * SD) return;
    int v = idx / SD, c = idx - v * SD;
    float w0 = LD<F32>(Wf3, c), w1 = LD<F32>(Wf3, SD + c), w2 = LD<F32>(Wf3, 2 * SD + c);
    float P = LD<F32>(pos, v * 3 + 0) * w0 + LD<F32>(pos, v * 3 + 1) * w1
            + LD<F32>(pos, v * 3 + 2) * w2;
    float D = dx[v * 3 + 0] * w0 + dx[v * 3 + 1] * w1 + dx[v * 3 + 2] * w2;
    ua[idx] += P;
    bbag[idx] = D - P;
}

// ---------- bbag[v] := max(0, (max_{e->v} ua[src]) + bbag[v]) ----------
__global__ __launch_bounds__(256) void k_aggr(
    const float* __restrict__ a, float* bbag,
    const int* __restrict__ offs, const int* __restrict__ esrc) {
    int wv = threadIdx.x >> 6, lane = threadIdx.x & 63;
    int v = blockIdx.x * 4 + wv;
    if (v >= N_V) return;
    int e0 = offs[v], e1 = offs[v + 1];
    float r0 = -3.0e38f, r1 = r0, r2 = r0, r3 = r0, r4 = r0;
    bool c4 = lane < SD - 256;
    for (int e = e0; e < e1; e++) {
        const float* ar = a + (size_t)esrc[e] * SD + lane;
        r0 = fmaxf(r0, ar[0]);
        r1 = fmaxf(r1, ar[64]);
        r2 = fmaxf(r2, ar[128]);
        r3 = fmaxf(r3, ar[192]);
        if (c4) r4 = fmaxf(r4, ar[256]);
    }
    float* bv = bbag + (size_t)v * SD + lane;
    bv[0]   = fmaxf(0.f, r0 + bv[0]);
    bv[64]  = fmaxf(0.f, r1 + bv[64]);
    bv[128] = fmaxf(0.f, r2 + bv[128]);
    bv[192] = fmaxf(0.f, r3 + bv[192]);
    if (c4) bv[256] = fmaxf(0.f, r4 + bv[256]);
}

// ---------- cls head layer2 ----------
template<bool F32>
__global__ void k_cls(const float* __restrict__ hc, const void* __restrict__ W,
                      const void* __restrict__ b, void* __restrict__ out,
                      const int* __restrict__ flag) {
    if ((flag[0] != 0) != F32) return;
    int v = blockIdx.x * blockDim.x + threadIdx.x;
    if (v >= N_V) return;
    float acc[4];
#pragma unroll
    for (int j = 0; j < 4; j++) acc[j] = LD<F32>(b, j);
    for (int k = 0; k < 64; k++) {
        float h = hc[(size_t)v * 64 + k];
#pragma unroll
        for (int j = 0; j < 4; j++) acc[j] += h * LD<F32>(W, k * 4 + j);
    }
#pragma unroll
    for (int j = 0; j < 4; j++) ST<F32>(out, v * 4 + j, fmaxf(acc[j], 0.f));
}

// ---------- loc head layer3 ----------
template<bool F32>
__global__ void k_loc3(const float* __restrict__ h2, const void* __restrict__ W,
                       const void* __restrict__ b, void* __restrict__ out, int cls,
                       const int* __restrict__ flag) {
    if ((flag[0] != 0) != F32) return;
    int v = blockIdx.x * blockDim.x + threadIdx.x;
    if (v >= N_V) return;
    float acc[7];
#pragma unroll
    for (int j = 0; j < 7; j++) acc[j] = LD<F32>(b, j);
    for (int k = 0; k < 64; k++) {
        float h = h2[(size_t)v * 64 + k];
#pragma unroll
        for (int j = 0; j < 7; j++) acc[j] += h * LD<F32>(W, k * 7 + j);
    }
#pragma unroll
    for (int j = 0; j < 7; j++)
        ST<F32>(out, 80000 + (size_t)v * 28 + cls * 7 + j, fmaxf(acc[j], 0.f));
}

#define LAUNCH2(kname, grid, blk, ...) \
    do { kname<false><<<grid, blk, 0, stream>>>(__VA_ARGS__); \
         kname<true><<<grid, blk, 0, stream>>>(__VA_ARGS__); } while (0)

extern "C" void kernel_launch(void* const* d_in, const int* in_sizes, int n_in,
                              void* d_out, int out_size, void* d_ws, size_t ws_size,
                              hipStream_t stream) {
    const void* kp  = d_in[0];
    const void* pos = d_in[1];
    const int* eidx = (const int*)d_in[3];
    const int* e_src = eidx;
    const int* e_dst = eidx + E_N;
    const void* Wi0 = d_in[4];   const void* bi0 = d_in[5];
    const void* Wi1 = d_in[6];   const void* bi1 = d_in[7];
    const void* Wi2 = d_in[8];   const void* bi2 = d_in[9];
    const void* Wa  = d_in[10];  const void* ba  = d_in[11];
    const char* Wh  = (const char*)d_in[12];  const char* bh = (const char*)d_in[13];
    const char* Wf  = (const char*)d_in[14];  const char* bff = (const char*)d_in[15];
    const char* Wg  = (const char*)d_in[16];  const char* bg = (const char*)d_in[17];
    const void* Wc1 = d_in[18];  const void* bc1 = d_in[19];
    const void* Wc2 = d_in[20];  const void* bc2 = d_in[21];
    const char* Wl1 = (const char*)d_in[22];  const char* bl1 = (const char*)d_in[23];
    const char* Wl2 = (const char*)d_in[24];  const char* bl2 = (const char*)d_in[25];
    const char* Wl3 = (const char*)d_in[26];  const char* bl3 = (const char*)d_in[27];

    char* ws = (char*)d_ws;
    // region A (24MB): kpmax (init) -> ua (GNN) -> hc/hl1/hl2 (heads)
    float* regA  = (float*)(ws + 0);
    float* kpmax = regA;
    float* ua    = regA;
    float* hc    = (float*)(ws + 0);
    float* hl1   = (float*)(ws + 6000000);
    float* hl2   = (float*)(ws + 12000000);
    // region B (24MB): bbag (b then aggr, aliased)
    float* bbag  = (float*)(ws + 24000000);
    // region C (24MB): s
    float* s     = (float*)(ws + 48000000);
    // small stuff
    int*   cnt   = (int*)(ws + 72000000);
    int*   offs  = (int*)(ws + 72100000);
    int*   cur   = (int*)(ws + 72200000);
    int*   esrc  = (int*)(ws + 72300000);
    float* dx    = (float*)(ws + 73600000);
    int*   flag  = (int*)(ws + 73900000);
    // total footprint < 74 MB

    // element stride between stacked per-iter / per-class weights, in BYTES,
    // depends on dtype; pass typed pointers computed per variant via helper:
    // we just compute both offsets inline at launch time using elem size 2 or 4.

    // ----- dtype detect -----
    k_detect<<<1, 128, 0, stream>>>((const unsigned*)Wi0, flag);

    // ----- CSR build -----
    k_zero<<<(N_V + 255) / 256, 256, 0, stream>>>(cnt, N_V);
    k_hist<<<(E_N + 255) / 256, 256, 0, stream>>>(e_dst, cnt);
    k_scan<<<1, 1024, 0, stream>>>(cnt, offs, cur);
    k_scatter<<<(E_N + 255) / 256, 256, 0, stream>>>(e_src, e_dst, cur, esrc);

    // ----- fused init MLP + segmax -----
    LAUNCH2(k_init_fused, M_KP / 64, 256, kp, Wi0, bi0, Wi1, bi1, Wi2, bi2, kpmax, flag);
    {
        dim3 g((SD + 63) / 64, (N_V + 63) / 64);
        LAUNCH2(k_gemm, g, 256, kpmax, Wa, ba, nullptr, s, N_V, SD, SD, 1, flag);
    }

    // ----- GNN iterations -----
    for (int t = 0; t < T_IT; t++) {
        dim3 g5((SD + 63) / 64, (N_V + 63) / 64);
        // per-variant typed offsets (elem size 2 for bf16, 4 for f32)
        for (int f32v = 0; f32v < 2; f32v++) {
            size_t es = f32v ? 4 : 2;
            const void* Wf_t = Wf + (size_t)t * 303 * SD * es;   // rows [0:3]=Wf3, [3:303]=WfS
            const void* WfS  = Wf + ((size_t)t * 303 + 3) * SD * es;
            const void* bf_t = bff + (size_t)t * SD * es;
            const void* Wh_t = Wh + (size_t)t * SD * 3 * es;
            const void* bh_t = bh + (size_t)t * 3 * es;
            const void* Wg_t = Wg + (size_t)t * SD * SD * es;
            const void* bg_t = bg + (size_t)t * SD * es;
            if (f32v) {
                k_gemm<true><<<g5, 256, 0, stream>>>(s, WfS, bf_t, nullptr, ua, N_V, SD, SD, 0, flag);
                k_dx<true><<<(N_V + 3) / 4, 256, 0, stream>>>(s, Wh_t, bh_t, dx, flag);
                k_ab<true><<<(N_V * SD + 255) / 256, 256, 0, stream>>>(dx, pos, Wf_t, ua, bbag, flag);
            } else {
                k_gemm<false><<<g5, 256, 0, stream>>>(s, WfS, bf_t, nullptr, ua, N_V, SD, SD, 0, flag);
                k_dx<false><<<(N_V + 3) / 4, 256, 0, stream>>>(s, Wh_t, bh_t, dx, flag);
                k_ab<false><<<(N_V * SD + 255) / 256, 256, 0, stream>>>(dx, pos, Wf_t, ua, bbag, flag);
            }
        }
        k_aggr<<<(N_V + 3) / 4, 256, 0, stream>>>(ua, bbag, offs, esrc);
        for (int f32v = 0; f32v < 2; f32v++) {
            size_t es = f32v ? 4 : 2;
            const void* Wg_t = Wg + (size_t)t * SD * SD * es;
            const void* bg_t = bg + (size_t)t * SD * es;
            if (f32v)
                k_gemm<true><<<g5, 256, 0, stream>>>(bbag, Wg_t, bg_t, s, s, N_V, SD, SD, 0, flag);
            else
                k_gemm<false><<<g5, 256, 0, stream>>>(bbag, Wg_t, bg_t, s, s, N_V, SD, SD, 0, flag);
        }
    }

    // ----- heads -----
    {
        dim3 g(1, (N_V + 63) / 64);
        LAUNCH2(k_gemm, g, 256, s, Wc1, bc1, nullptr, hc, N_V, SD, 64, 1, flag);
    }
    LAUNCH2(k_cls, (N_V + 255) / 256, 256, hc, Wc2, bc2, d_out, flag);
    for (int c = 0; c < 4; c++) {
        dim3 g(1, (N_V + 63) / 64);
        for (int f32v = 0; f32v < 2; f32v++) {
            size_t es = f32v ? 4 : 2;
            const void* Wl1c = Wl1 + (size_t)c * SD * 64 * es;
            const void* bl1c = bl1 + (size_t)c * 64 * es;
            const void* Wl2c = Wl2 + (size_t)c * 64 * 64 * es;
            const void* bl2c = bl2 + (size_t)c * 64 * es;
            const void* Wl3c = Wl3 + (size_t)c * 64 * 7 * es;
            const void* bl3c = bl3 + (size_t)c * 7 * es;
            if (f32v) {
                k_gemm<true><<<g, 256, 0, stream>>>(s, Wl1c, bl1c, nullptr, hl1, N_V, SD, 64, 1, flag);
                k_gemm<true><<<g, 256, 0, stream>>>(hl1, Wl2c, bl2c, nullptr, hl2, N_V, 64, 64, 1, flag);
                k_loc3<true><<<(N_V + 255) / 256, 256, 0, stream>>>(hl2, Wl3c, bl3c, d_out, c, flag);
            } else {
                k_gemm<false><<<g, 256, 0, stream>>>(s, Wl1c, bl1c, nullptr, hl1, N_V, SD, 64, 1, flag);
                k_gemm<false><<<g, 256, 0, stream>>>(hl1, Wl2c, bl2c, nullptr, hl2, N_V, 64, 64, 1, flag);
                k_loc3<false><<<(N_V + 255) / 256, 256, 0, stream>>>(hl2, Wl3c, bl3c, d_out, c, flag);
            }
        }
    }
}